// Round 1
// baseline (399.838 us; speedup 1.0000x reference)
//
#include <hip/hip_runtime.h>
#include <hip/hip_bf16.h>

// Problem constants
#define HDIM 1024
#define SEQ  2048
#define BATCH 16
#define VOCAB 250002
#define M_TOT (BATCH * SEQ)                 // 32768 rows
#define DENSE_OFF 0
#define SPARSE_OFF (BATCH * HDIM)           // 16384
#define COLBERT_OFF (SPARSE_OFF + BATCH * VOCAB)  // 4016416
#define COLBERT_ROWS (BATCH * (SEQ - 1))    // 32752

typedef __attribute__((ext_vector_type(8))) short short8;   // 8 bf16 (4 VGPRs)
typedef __attribute__((ext_vector_type(4))) float f32x4;

static __device__ __forceinline__ unsigned short f2bf(float f) {
  union { float f; unsigned u; } v; v.f = f;
  unsigned r = v.u + 0x7fffu + ((v.u >> 16) & 1u);  // RNE
  return (unsigned short)(r >> 16);
}

// ---------------------------------------------------------------------------
// Kernel 1: cast hidden fp32 -> bf16 (for GEMM) + sparse token weight + scatter-max
// One wave per token row (1024 elems). 4 waves / block. Grid = 32768/4 = 8192.
// ---------------------------------------------------------------------------
__global__ __launch_bounds__(256) void cast_sparse_kernel(
    const float* __restrict__ hidden,
    const float* __restrict__ sparse_W,
    const float* __restrict__ sparse_b,
    const int* __restrict__ input_ids,
    unsigned short* __restrict__ hidden_bf,   // (32768, 1024) bf16 bits
    float* __restrict__ sparse_out)           // (B, VOCAB), pre-zeroed
{
  const int token = blockIdx.x * 4 + (threadIdx.x >> 6);
  const int lane = threadIdx.x & 63;

  const float4* xr = (const float4*)(hidden + (size_t)token * HDIM);
  const float4* wr = (const float4*)sparse_W;
  ushort4* hb = (ushort4*)(hidden_bf + (size_t)token * HDIM);

  float dot = 0.0f;
#pragma unroll
  for (int i = 0; i < 4; i++) {
    const int idx = i * 64 + lane;      // coalesced float4 per instruction
    float4 xv = xr[idx];
    float4 wv = wr[idx];
    dot = fmaf(xv.x, wv.x, dot);
    dot = fmaf(xv.y, wv.y, dot);
    dot = fmaf(xv.z, wv.z, dot);
    dot = fmaf(xv.w, wv.w, dot);
    ushort4 o;
    o.x = f2bf(xv.x); o.y = f2bf(xv.y); o.z = f2bf(xv.z); o.w = f2bf(xv.w);
    hb[idx] = o;
  }
  // wave-64 reduce
#pragma unroll
  for (int off = 32; off; off >>= 1) dot += __shfl_down(dot, off);

  if (lane == 0) {
    float w = dot + sparse_b[0];
    if (w > 0.0f) {                      // relu; 0 needs no scatter (init is 0)
      int id = input_ids[token];
      if (id > 3) {                      // UNUSED_TOKEN_IDS = {0,1,2,3}
        int b = token >> 11;             // token / SEQ
        atomicMax((int*)(sparse_out + (size_t)b * VOCAB + id), __float_as_int(w));
      }
    }
  }
}

// ---------------------------------------------------------------------------
// Kernel 2: dense head — L2-normalize CLS rows. 16 blocks x 256 threads.
// ---------------------------------------------------------------------------
__global__ __launch_bounds__(256) void dense_kernel(
    const float* __restrict__ hidden, float* __restrict__ out)
{
  const int b = blockIdx.x;
  const int t = threadIdx.x;
  const float4* x = (const float4*)(hidden + (size_t)b * SEQ * HDIM);
  float4 v = x[t];
  float ss = v.x * v.x + v.y * v.y + v.z * v.z + v.w * v.w;
#pragma unroll
  for (int off = 32; off; off >>= 1) ss += __shfl_down(ss, off);
  __shared__ float red[4];
  if ((t & 63) == 0) red[t >> 6] = ss;
  __syncthreads();
  float tot = red[0] + red[1] + red[2] + red[3];
  float inv = 1.0f / fmaxf(sqrtf(tot), 1e-12f);
  v.x *= inv; v.y *= inv; v.z *= inv; v.w *= inv;
  ((float4*)(out + (size_t)b * HDIM))[t] = v;
}

// ---------------------------------------------------------------------------
// Kernel 3: transpose colbert_W (k,n) fp32 -> Wt (n,k) bf16 so GEMM B-operand
// stages contiguously along K (global_load_lds needs contiguous LDS rows).
// ---------------------------------------------------------------------------
__global__ __launch_bounds__(256) void transpose_w_kernel(
    const float* __restrict__ W, unsigned short* __restrict__ Wt)
{
  __shared__ float tile[32][33];
  const int n0 = blockIdx.x * 32, k0 = blockIdx.y * 32;
  const int tx = threadIdx.x, ty = threadIdx.y;   // block (32, 8)
#pragma unroll
  for (int i = ty; i < 32; i += 8)
    tile[i][tx] = W[(size_t)(k0 + i) * HDIM + n0 + tx];
  __syncthreads();
#pragma unroll
  for (int i = ty; i < 32; i += 8)
    Wt[(size_t)(n0 + i) * HDIM + k0 + tx] = f2bf(tile[tx][i]);
}

// ---------------------------------------------------------------------------
// Kernel 4: GEMM  C = A(32768x1024 bf16) * W(1024x1024) + bias, m97 structure:
// 128x128 tile, BK=32, 4 waves each 64x64 (4x4 MFMA 16x16x32), global_load_lds
// width 16. Writes fp32 directly to d_out colbert region (skips s==0 rows).
// ---------------------------------------------------------------------------
__global__ __launch_bounds__(256) void gemm_colbert_kernel(
    const unsigned short* __restrict__ Abf,   // (32768, 1024) row-major (m,k)
    const unsigned short* __restrict__ Btbf,  // (1024, 1024) row-major (n,k)
    const float* __restrict__ bias,           // (1024,)
    float* __restrict__ out)                  // d_out base
{
  __shared__ __attribute__((aligned(16))) unsigned short As[128 * 32];
  __shared__ __attribute__((aligned(16))) unsigned short Bs[128 * 32];

  const int t = threadIdx.x;
  const int wv = t >> 6, l = t & 63;
  const int nt = blockIdx.x & 7, mt = blockIdx.x >> 3;
  const int mBase = mt * 128, nBase = nt * 128;
  const int wm = wv >> 1, wn = wv & 1;
  const int q = l >> 4, ml = l & 15;

  f32x4 acc[4][4] = {};

  const int c0 = t;            // 16B chunk ids (512 per matrix per K-step)
  const int c1 = t + 256;
  const unsigned short* Ab = Abf + (size_t)mBase * HDIM;
  const unsigned short* Bb = Btbf + (size_t)nBase * HDIM;
  // chunk c: row = c>>2, k-elem-offset = (c&3)*8. LDS elem offset = c*8.
  const size_t ga0 = (size_t)(c0 >> 2) * HDIM + (c0 & 3) * 8;
  const size_t ga1 = (size_t)(c1 >> 2) * HDIM + (c1 & 3) * 8;

  for (int k0 = 0; k0 < HDIM; k0 += 32) {
    __builtin_amdgcn_global_load_lds(
        (const __attribute__((address_space(1))) unsigned int*)(Ab + k0 + ga0),
        (__attribute__((address_space(3))) unsigned int*)(As + wv * 512), 16, 0, 0);
    __builtin_amdgcn_global_load_lds(
        (const __attribute__((address_space(1))) unsigned int*)(Ab + k0 + ga1),
        (__attribute__((address_space(3))) unsigned int*)(As + 2048 + wv * 512), 16, 0, 0);
    __builtin_amdgcn_global_load_lds(
        (const __attribute__((address_space(1))) unsigned int*)(Bb + k0 + ga0),
        (__attribute__((address_space(3))) unsigned int*)(Bs + wv * 512), 16, 0, 0);
    __builtin_amdgcn_global_load_lds(
        (const __attribute__((address_space(1))) unsigned int*)(Bb + k0 + ga1),
        (__attribute__((address_space(3))) unsigned int*)(Bs + 2048 + wv * 512), 16, 0, 0);
    __syncthreads();

    short8 af[4], bf[4];
#pragma unroll
    for (int i = 0; i < 4; i++) {
      af[i] = *(const short8*)(As + (wm * 64 + i * 16 + ml) * 32 + q * 8);
      bf[i] = *(const short8*)(Bs + (wn * 64 + i * 16 + ml) * 32 + q * 8);
    }
#pragma unroll
    for (int i = 0; i < 4; i++)
#pragma unroll
      for (int j = 0; j < 4; j++)
        acc[i][j] = __builtin_amdgcn_mfma_f32_16x16x32_bf16(af[i], bf[j], acc[i][j], 0, 0, 0);
    __syncthreads();
  }

  // epilogue: + bias, scatter to colbert region (drop s==0 rows)
#pragma unroll
  for (int j = 0; j < 4; j++) {
    const int gn = nBase + wn * 64 + j * 16 + ml;
    const float bv = bias[gn];
#pragma unroll
    for (int i = 0; i < 4; i++) {
#pragma unroll
      for (int r = 0; r < 4; r++) {
        const int gm = mBase + wm * 64 + i * 16 + q * 4 + r;
        const int s = gm & (SEQ - 1);
        if (s != 0) {
          const int b = gm >> 11;
          out[COLBERT_OFF + (size_t)(b * (SEQ - 1) + s - 1) * HDIM + gn] =
              acc[i][j][r] + bv;
        }
      }
    }
  }
}

// ---------------------------------------------------------------------------
// Kernel 5: in-place mask + L2-normalize colbert rows. One block per row.
// ---------------------------------------------------------------------------
__global__ __launch_bounds__(256) void colbert_norm_kernel(
    float* __restrict__ out, const float* __restrict__ mask)
{
  const int row = blockIdx.x;              // 0..32751
  const int b = row / (SEQ - 1);
  const int s = row - b * (SEQ - 1) + 1;   // 1..2047
  const float mval = mask[b * SEQ + s];

  float4* p = (float4*)(out + COLBERT_OFF + (size_t)row * HDIM);
  float4 v = p[threadIdx.x];
  v.x *= mval; v.y *= mval; v.z *= mval; v.w *= mval;
  float ss = v.x * v.x + v.y * v.y + v.z * v.z + v.w * v.w;
#pragma unroll
  for (int off = 32; off; off >>= 1) ss += __shfl_down(ss, off);
  __shared__ float red[4];
  if ((threadIdx.x & 63) == 0) red[threadIdx.x >> 6] = ss;
  __syncthreads();
  float tot = red[0] + red[1] + red[2] + red[3];
  float inv = 1.0f / fmaxf(sqrtf(tot), 1e-12f);
  v.x *= inv; v.y *= inv; v.z *= inv; v.w *= inv;
  p[threadIdx.x] = v;
}

// ---------------------------------------------------------------------------
extern "C" void kernel_launch(void* const* d_in, const int* in_sizes, int n_in,
                              void* d_out, int out_size, void* d_ws, size_t ws_size,
                              hipStream_t stream) {
  (void)in_sizes; (void)n_in; (void)out_size; (void)ws_size;
  const float* hidden = (const float*)d_in[0];
  const float* attn_mask = (const float*)d_in[1];
  const int* input_ids = (const int*)d_in[2];
  const float* sparse_W = (const float*)d_in[3];
  const float* sparse_b = (const float*)d_in[4];
  const float* colbert_W = (const float*)d_in[5];
  const float* colbert_b = (const float*)d_in[6];
  float* out = (float*)d_out;

  unsigned short* hidden_bf = (unsigned short*)d_ws;                       // 64 MiB
  unsigned short* Wt = (unsigned short*)((char*)d_ws + (size_t)M_TOT * HDIM * 2);

  // zero the sparse region (scatter-max baseline; also zeroes unused-token slots)
  hipMemsetAsync(out + SPARSE_OFF, 0, (size_t)BATCH * VOCAB * sizeof(float), stream);

  cast_sparse_kernel<<<M_TOT / 4, 256, 0, stream>>>(
      hidden, sparse_W, sparse_b, input_ids, hidden_bf, out + SPARSE_OFF);
  transpose_w_kernel<<<dim3(32, 32), dim3(32, 8), 0, stream>>>(colbert_W, Wt);
  dense_kernel<<<BATCH, 256, 0, stream>>>(hidden, out);
  gemm_colbert_kernel<<<(M_TOT / 128) * (HDIM / 128), 256, 0, stream>>>(
      hidden_bf, Wt, colbert_b, out);
  colbert_norm_kernel<<<COLBERT_ROWS, 256, 0, stream>>>(out, attn_mask);
}

// Round 2
// 382.468 us; speedup vs baseline: 1.0454x; 1.0454x over previous
//
#include <hip/hip_runtime.h>
#include <hip/hip_bf16.h>

// Problem constants
#define HDIM 1024
#define SEQ  2048
#define BATCH 16
#define VOCAB 250002
#define M_TOT (BATCH * SEQ)                 // 32768 rows
#define DENSE_OFF 0
#define SPARSE_OFF (BATCH * HDIM)           // 16384
#define COLBERT_OFF (SPARSE_OFF + BATCH * VOCAB)  // 4016416
#define COLBERT_ROWS (BATCH * (SEQ - 1))    // 32752

typedef __attribute__((ext_vector_type(8))) short short8;   // 8 bf16 (4 VGPRs)
typedef __attribute__((ext_vector_type(4))) float f32x4;

static __device__ __forceinline__ unsigned short f2bf(float f) {
  union { float f; unsigned u; } v; v.f = f;
  unsigned r = v.u + 0x7fffu + ((v.u >> 16) & 1u);  // RNE
  return (unsigned short)(r >> 16);
}

// ---------------------------------------------------------------------------
// Kernel 1: cast hidden fp32 -> bf16 (for GEMM) + sparse token weight + scatter-max
// One wave per token row (1024 elems). 4 waves / block. Grid = 32768/4 = 8192.
// ---------------------------------------------------------------------------
__global__ __launch_bounds__(256) void cast_sparse_kernel(
    const float* __restrict__ hidden,
    const float* __restrict__ sparse_W,
    const float* __restrict__ sparse_b,
    const int* __restrict__ input_ids,
    unsigned short* __restrict__ hidden_bf,   // (32768, 1024) bf16 bits
    float* __restrict__ sparse_out)           // (B, VOCAB), pre-zeroed
{
  const int token = blockIdx.x * 4 + (threadIdx.x >> 6);
  const int lane = threadIdx.x & 63;

  const float4* xr = (const float4*)(hidden + (size_t)token * HDIM);
  const float4* wr = (const float4*)sparse_W;
  ushort4* hb = (ushort4*)(hidden_bf + (size_t)token * HDIM);

  float dot = 0.0f;
#pragma unroll
  for (int i = 0; i < 4; i++) {
    const int idx = i * 64 + lane;      // coalesced float4 per instruction
    float4 xv = xr[idx];
    float4 wv = wr[idx];
    dot = fmaf(xv.x, wv.x, dot);
    dot = fmaf(xv.y, wv.y, dot);
    dot = fmaf(xv.z, wv.z, dot);
    dot = fmaf(xv.w, wv.w, dot);
    ushort4 o;
    o.x = f2bf(xv.x); o.y = f2bf(xv.y); o.z = f2bf(xv.z); o.w = f2bf(xv.w);
    hb[idx] = o;
  }
  // wave-64 reduce
#pragma unroll
  for (int off = 32; off; off >>= 1) dot += __shfl_down(dot, off);

  if (lane == 0) {
    float w = dot + sparse_b[0];
    if (w > 0.0f) {                      // relu; 0 needs no scatter (init is 0)
      int id = input_ids[token];
      if (id > 3) {                      // UNUSED_TOKEN_IDS = {0,1,2,3}
        int b = token >> 11;             // token / SEQ
        atomicMax((int*)(sparse_out + (size_t)b * VOCAB + id), __float_as_int(w));
      }
    }
  }
}

// ---------------------------------------------------------------------------
// Kernel 2: dense head — L2-normalize CLS rows. 16 blocks x 256 threads.
// ---------------------------------------------------------------------------
__global__ __launch_bounds__(256) void dense_kernel(
    const float* __restrict__ hidden, float* __restrict__ out)
{
  const int b = blockIdx.x;
  const int t = threadIdx.x;
  const float4* x = (const float4*)(hidden + (size_t)b * SEQ * HDIM);
  float4 v = x[t];
  float ss = v.x * v.x + v.y * v.y + v.z * v.z + v.w * v.w;
#pragma unroll
  for (int off = 32; off; off >>= 1) ss += __shfl_down(ss, off);
  __shared__ float red[4];
  if ((t & 63) == 0) red[t >> 6] = ss;
  __syncthreads();
  float tot = red[0] + red[1] + red[2] + red[3];
  float inv = 1.0f / fmaxf(sqrtf(tot), 1e-12f);
  v.x *= inv; v.y *= inv; v.z *= inv; v.w *= inv;
  ((float4*)(out + (size_t)b * HDIM))[t] = v;
}

// ---------------------------------------------------------------------------
// Kernel 3: transpose colbert_W (k,n) fp32 -> Wt (n,k) bf16 so GEMM B-operand
// stages contiguously along K (global_load_lds needs contiguous LDS rows).
// ---------------------------------------------------------------------------
__global__ __launch_bounds__(256) void transpose_w_kernel(
    const float* __restrict__ W, unsigned short* __restrict__ Wt)
{
  __shared__ float tile[32][33];
  const int n0 = blockIdx.x * 32, k0 = blockIdx.y * 32;
  const int tx = threadIdx.x, ty = threadIdx.y;   // block (32, 8)
#pragma unroll
  for (int i = ty; i < 32; i += 8)
    tile[i][tx] = W[(size_t)(k0 + i) * HDIM + n0 + tx];
  __syncthreads();
#pragma unroll
  for (int i = ty; i < 32; i += 8)
    Wt[(size_t)(n0 + i) * HDIM + k0 + tx] = f2bf(tile[tx][i]);
}

// ---------------------------------------------------------------------------
// Kernel 4: GEMM  C = A(32768x1024 bf16) * W(1024x1024) + bias.
// 128x128 tile, BK=32, 4 waves each 64x64 (4x4 MFMA 16x16x32), global_load_lds
// width 16. XCD-aware swizzle: blocks sharing an A-panel land on one XCD's L2.
// LDS rotate-swizzle: slot = (kc + row/2) & 3 — spreads ds_read_b128 across
// all 8 bank-groups (2-way = free) instead of 2 groups (8-way = 2.94x).
// ---------------------------------------------------------------------------
__global__ __launch_bounds__(256) void gemm_colbert_kernel(
    const unsigned short* __restrict__ Abf,   // (32768, 1024) row-major (m,k)
    const unsigned short* __restrict__ Btbf,  // (1024, 1024) row-major (n,k)
    const float* __restrict__ bias,           // (1024,)
    float* __restrict__ out)                  // d_out base
{
  __shared__ __attribute__((aligned(16))) unsigned short As[128 * 32];
  __shared__ __attribute__((aligned(16))) unsigned short Bs[128 * 32];

  const int t = threadIdx.x;
  const int wv = t >> 6, l = t & 63;

  // XCD-aware swizzle: dispatch is round-robin over 8 XCDs (blockIdx % 8).
  // Give each XCD 32 contiguous m-tiles, n fastest -> the 8 blocks sharing an
  // A-panel run back-to-back on the same XCD's L2.
  const int xcd = blockIdx.x & 7;
  const int local = blockIdx.x >> 3;        // 0..255
  const int mt = xcd * 32 + (local >> 3);   // 0..255
  const int nt = local & 7;
  const int mBase = mt * 128, nBase = nt * 128;
  const int wm = wv >> 1, wn = wv & 1;
  const int q = l >> 4, ml = l & 15;

  f32x4 acc[4][4] = {};

  // Staging: LDS 16B-chunk ci holds global chunk (row=ci>>2, kc=(slot - row/2)&3)
  // where slot=ci&3.  Read side: row r, kchunk q lives at slot (q + r/2)&3.
  const int c0 = t;            // 512 chunks per matrix per K-step
  const int c1 = t + 256;
  const int r0 = c0 >> 2, r1 = c1 >> 2;
  const size_t ga0 = (size_t)r0 * HDIM + (((c0 & 3) - (r0 >> 1)) & 3) * 8;
  const size_t ga1 = (size_t)r1 * HDIM + (((c1 & 3) - (r1 >> 1)) & 3) * 8;

  const unsigned short* Ab = Abf + (size_t)mBase * HDIM;
  const unsigned short* Bb = Btbf + (size_t)nBase * HDIM;

  for (int k0 = 0; k0 < HDIM; k0 += 32) {
    __builtin_amdgcn_global_load_lds(
        (const __attribute__((address_space(1))) unsigned int*)(Ab + k0 + ga0),
        (__attribute__((address_space(3))) unsigned int*)(As + wv * 512), 16, 0, 0);
    __builtin_amdgcn_global_load_lds(
        (const __attribute__((address_space(1))) unsigned int*)(Ab + k0 + ga1),
        (__attribute__((address_space(3))) unsigned int*)(As + 2048 + wv * 512), 16, 0, 0);
    __builtin_amdgcn_global_load_lds(
        (const __attribute__((address_space(1))) unsigned int*)(Bb + k0 + ga0),
        (__attribute__((address_space(3))) unsigned int*)(Bs + wv * 512), 16, 0, 0);
    __builtin_amdgcn_global_load_lds(
        (const __attribute__((address_space(1))) unsigned int*)(Bb + k0 + ga1),
        (__attribute__((address_space(3))) unsigned int*)(Bs + 2048 + wv * 512), 16, 0, 0);
    __syncthreads();

    short8 af[4], bf[4];
#pragma unroll
    for (int i = 0; i < 4; i++) {
      const int ar = wm * 64 + i * 16 + ml;
      const int br = wn * 64 + i * 16 + ml;
      af[i] = *(const short8*)(As + ar * 32 + (((q + (ar >> 1)) & 3) * 8));
      bf[i] = *(const short8*)(Bs + br * 32 + (((q + (br >> 1)) & 3) * 8));
    }
#pragma unroll
    for (int i = 0; i < 4; i++)
#pragma unroll
      for (int j = 0; j < 4; j++)
        acc[i][j] = __builtin_amdgcn_mfma_f32_16x16x32_bf16(af[i], bf[j], acc[i][j], 0, 0, 0);
    __syncthreads();
  }

  // epilogue: + bias, scatter to colbert region (drop s==0 rows)
#pragma unroll
  for (int j = 0; j < 4; j++) {
    const int gn = nBase + wn * 64 + j * 16 + ml;
    const float bv = bias[gn];
#pragma unroll
    for (int i = 0; i < 4; i++) {
#pragma unroll
      for (int r = 0; r < 4; r++) {
        const int gm = mBase + wm * 64 + i * 16 + q * 4 + r;
        const int s = gm & (SEQ - 1);
        if (s != 0) {
          const int b = gm >> 11;
          out[COLBERT_OFF + (size_t)(b * (SEQ - 1) + s - 1) * HDIM + gn] =
              acc[i][j][r] + bv;
        }
      }
    }
  }
}

// ---------------------------------------------------------------------------
// Kernel 5: in-place mask + L2-normalize colbert rows. One row per WAVE —
// no __syncthreads, butterfly shfl_xor reduce. 4 rows/block, 8188 blocks.
// ---------------------------------------------------------------------------
__global__ __launch_bounds__(256) void colbert_norm_kernel(
    float* __restrict__ out, const float* __restrict__ mask)
{
  const int row = blockIdx.x * 4 + (threadIdx.x >> 6);  // 0..32751
  const int lane = threadIdx.x & 63;
  const int b = row / (SEQ - 1);
  const int s = row - b * (SEQ - 1) + 1;   // 1..2047
  const float mval = mask[b * SEQ + s];

  float4* p = (float4*)(out + COLBERT_OFF + (size_t)row * HDIM);
  float4 v[4];
  float ss = 0.0f;
#pragma unroll
  for (int i = 0; i < 4; i++) {
    v[i] = p[i * 64 + lane];
    ss += v[i].x * v[i].x + v[i].y * v[i].y + v[i].z * v[i].z + v[i].w * v[i].w;
  }
#pragma unroll
  for (int off = 32; off; off >>= 1) ss += __shfl_xor(ss, off);
  // result = x*mval / max(|mval|*||x||, eps)
  const float inv = mval / fmaxf(fabsf(mval) * sqrtf(ss), 1e-12f);
#pragma unroll
  for (int i = 0; i < 4; i++) {
    v[i].x *= inv; v[i].y *= inv; v[i].z *= inv; v[i].w *= inv;
    p[i * 64 + lane] = v[i];
  }
}

// ---------------------------------------------------------------------------
extern "C" void kernel_launch(void* const* d_in, const int* in_sizes, int n_in,
                              void* d_out, int out_size, void* d_ws, size_t ws_size,
                              hipStream_t stream) {
  (void)in_sizes; (void)n_in; (void)out_size; (void)ws_size;
  const float* hidden = (const float*)d_in[0];
  const float* attn_mask = (const float*)d_in[1];
  const int* input_ids = (const int*)d_in[2];
  const float* sparse_W = (const float*)d_in[3];
  const float* sparse_b = (const float*)d_in[4];
  const float* colbert_W = (const float*)d_in[5];
  const float* colbert_b = (const float*)d_in[6];
  float* out = (float*)d_out;

  unsigned short* hidden_bf = (unsigned short*)d_ws;                       // 64 MiB
  unsigned short* Wt = (unsigned short*)((char*)d_ws + (size_t)M_TOT * HDIM * 2);

  // zero the sparse region (scatter-max baseline; also zeroes unused-token slots)
  hipMemsetAsync(out + SPARSE_OFF, 0, (size_t)BATCH * VOCAB * sizeof(float), stream);

  cast_sparse_kernel<<<M_TOT / 4, 256, 0, stream>>>(
      hidden, sparse_W, sparse_b, input_ids, hidden_bf, out + SPARSE_OFF);
  transpose_w_kernel<<<dim3(32, 32), dim3(32, 8), 0, stream>>>(colbert_W, Wt);
  dense_kernel<<<BATCH, 256, 0, stream>>>(hidden, out);
  gemm_colbert_kernel<<<(M_TOT / 128) * (HDIM / 128), 256, 0, stream>>>(
      hidden_bf, Wt, colbert_b, out);
  colbert_norm_kernel<<<COLBERT_ROWS / 4, 256, 0, stream>>>(out, attn_mask);
}

// Round 3
// 375.633 us; speedup vs baseline: 1.0644x; 1.0182x over previous
//
#include <hip/hip_runtime.h>
#include <hip/hip_bf16.h>

// Problem constants
#define HDIM 1024
#define SEQ  2048
#define BATCH 16
#define VOCAB 250002
#define M_TOT (BATCH * SEQ)                 // 32768 rows
#define SPARSE_OFF (BATCH * HDIM)           // 16384
#define COLBERT_OFF (SPARSE_OFF + BATCH * VOCAB)  // 4016416

typedef __attribute__((ext_vector_type(8))) short short8;   // 8 bf16 (4 VGPRs)
typedef __attribute__((ext_vector_type(4))) float f32x4;

static __device__ __forceinline__ unsigned short f2bf(float f) {
  union { float f; unsigned u; } v; v.f = f;
  unsigned r = v.u + 0x7fffu + ((v.u >> 16) & 1u);  // RNE
  return (unsigned short)(r >> 16);
}

static __device__ __forceinline__ void gll16(const unsigned short* g, unsigned short* l) {
  __builtin_amdgcn_global_load_lds(
      (const __attribute__((address_space(1))) unsigned int*)g,
      (__attribute__((address_space(3))) unsigned int*)l, 16, 0, 0);
}

// ---------------------------------------------------------------------------
// Kernel 1 (prep): blocks 0..1023 transpose W fp32(k,n) -> bf16 Wt(n,k);
// blocks 1024..1535 zero the sparse output region; blocks 1536..1551 dense head.
// ---------------------------------------------------------------------------
__global__ __launch_bounds__(256) void prep_kernel(
    const float* __restrict__ W, unsigned short* __restrict__ Wt,
    float* __restrict__ out, const float* __restrict__ hidden)
{
  __shared__ float tile[32][33];
  __shared__ float red[4];
  const int blk = blockIdx.x;
  if (blk < 1024) {
    // transpose (32x32 tile); block laid out as 256 = 32x8
    const int n0 = (blk & 31) * 32, k0 = (blk >> 5) * 32;
    const int tx = threadIdx.x & 31, ty = threadIdx.x >> 5;   // 32 x 8
#pragma unroll
    for (int i = ty; i < 32; i += 8)
      tile[i][tx] = W[(size_t)(k0 + i) * HDIM + n0 + tx];
    __syncthreads();
#pragma unroll
    for (int i = ty; i < 32; i += 8)
      Wt[(size_t)(n0 + i) * HDIM + k0 + tx] = f2bf(tile[tx][i]);
  } else if (blk < 1536) {
    // zero sparse region: 4000032 floats = 1000008 float4
    float4 z = {0.f, 0.f, 0.f, 0.f};
    float4* p = (float4*)(out + SPARSE_OFF);
    int idx = (blk - 1024) * 256 + threadIdx.x;
#pragma unroll 1
    for (; idx < 1000008; idx += 512 * 256) p[idx] = z;
  } else {
    // dense head: L2-normalize CLS row of batch b
    const int b = blk - 1536;
    const int t = threadIdx.x;
    const float4* x = (const float4*)(hidden + (size_t)b * SEQ * HDIM);
    float4 v = x[t];
    float ss = v.x * v.x + v.y * v.y + v.z * v.z + v.w * v.w;
#pragma unroll
    for (int off = 32; off; off >>= 1) ss += __shfl_down(ss, off);
    if ((t & 63) == 0) red[t >> 6] = ss;
    __syncthreads();
    float tot = red[0] + red[1] + red[2] + red[3];
    float inv = 1.0f / fmaxf(sqrtf(tot), 1e-12f);
    v.x *= inv; v.y *= inv; v.z *= inv; v.w *= inv;
    ((float4*)(out + (size_t)b * HDIM))[t] = v;
  }
}

// ---------------------------------------------------------------------------
// Kernel 2: cast hidden fp32 -> bf16 + sparse token weight + scatter-max.
// One wave per token row. 4 waves / block. Grid = 8192.
// ---------------------------------------------------------------------------
__global__ __launch_bounds__(256) void cast_sparse_kernel(
    const float* __restrict__ hidden,
    const float* __restrict__ sparse_W,
    const float* __restrict__ sparse_b,
    const int* __restrict__ input_ids,
    unsigned short* __restrict__ hidden_bf,
    float* __restrict__ sparse_out)           // pre-zeroed by prep
{
  const int token = blockIdx.x * 4 + (threadIdx.x >> 6);
  const int lane = threadIdx.x & 63;

  const float4* xr = (const float4*)(hidden + (size_t)token * HDIM);
  const float4* wr = (const float4*)sparse_W;
  ushort4* hb = (ushort4*)(hidden_bf + (size_t)token * HDIM);

  float dot = 0.0f;
#pragma unroll
  for (int i = 0; i < 4; i++) {
    const int idx = i * 64 + lane;
    float4 xv = xr[idx];
    float4 wv = wr[idx];
    dot = fmaf(xv.x, wv.x, dot);
    dot = fmaf(xv.y, wv.y, dot);
    dot = fmaf(xv.z, wv.z, dot);
    dot = fmaf(xv.w, wv.w, dot);
    ushort4 o;
    o.x = f2bf(xv.x); o.y = f2bf(xv.y); o.z = f2bf(xv.z); o.w = f2bf(xv.w);
    hb[idx] = o;
  }
#pragma unroll
  for (int off = 32; off; off >>= 1) dot += __shfl_down(dot, off);

  if (lane == 0) {
    float w = dot + sparse_b[0];
    if (w > 0.0f) {
      int id = input_ids[token];
      if (id > 3) {                      // UNUSED_TOKEN_IDS = {0,1,2,3}
        int b = token >> 11;
        atomicMax((int*)(sparse_out + (size_t)b * VOCAB + id), __float_as_int(w));
      }
    }
  }
}

// ---------------------------------------------------------------------------
// Kernel 3: fused GEMM + bias + mask + L2-norm.
// Tile M=64 x N=1024 (full row -> norm fusable), BK=32, 512 threads (8 waves,
// each 64x128 via 4x8 MFMA 16x16x32). Double-buffered LDS (136 KB dynamic):
// with 1 block/CU there is no inter-block overlap, so prefetch of K-step k+1
// is issued before compute of k; the barrier's vmcnt(0) drain then overlaps
// with the whole MFMA phase. Rotate swizzle slot=(kc+row/2)&3 keeps ds_read
// conflict-free (verified 0 conflicts in round 2).
// ---------------------------------------------------------------------------
#define BS_ELEMS (1024 * 32)
#define AS_ELEMS (64 * 32)
#define LDS_BYTES ((2 * BS_ELEMS + 2 * AS_ELEMS) * 2)

__global__ __launch_bounds__(512, 2) void gemm_norm_kernel(
    const unsigned short* __restrict__ Abf,   // (32768, 1024) bf16 (m,k)
    const unsigned short* __restrict__ Btbf,  // (1024, 1024) bf16 (n,k)
    const float* __restrict__ bias,           // (1024,)
    const float* __restrict__ mask,           // (B, S)
    float* __restrict__ out)
{
  extern __shared__ __align__(16) char smem[];
  unsigned short* Bs0 = (unsigned short*)smem;
  unsigned short* Bs1 = Bs0 + BS_ELEMS;
  unsigned short* As0 = Bs1 + BS_ELEMS;
  unsigned short* As1 = As0 + AS_ELEMS;
  float* redLDS = (float*)smem;          // [64][8] — reused after K-loop
  float* invLDS = (float*)smem + 64 * 8; // [64]

  const int t = threadIdx.x;
  const int wv = t >> 6, l = t & 63;
  const int q = l >> 4, ml = l & 15;
  const int mBase = blockIdx.x * 64;

  // Staging source offsets (elements). B chunk cb = c*512 + wv*64 + l:
  // n = cb>>2, slot = cb&3, global k-chunk kc = (slot - n/2) & 3.
  int boff[8];
#pragma unroll
  for (int c = 0; c < 8; c++) {
    int cb = c * 512 + wv * 64 + l;
    int n = cb >> 2;
    int kc = ((cb & 3) - (n >> 1)) & 3;
    boff[c] = n * HDIM + kc * 8;
  }
  int aoff;
  {
    int ca = wv * 64 + l;              // valid for wv < 4
    int row = ca >> 2;
    int kc = ((ca & 3) - (row >> 1)) & 3;
    aoff = (mBase + row) * HDIM + kc * 8;
  }

  f32x4 acc[4][8] = {};

#define STAGE(K0, BD, AD)                                               \
  do {                                                                  \
    _Pragma("unroll")                                                   \
    for (int c = 0; c < 8; c++)                                         \
      gll16(Btbf + boff[c] + (K0), (BD) + (c * 512 + wv * 64) * 8);     \
    if (wv < 4) gll16(Abf + aoff + (K0), (AD) + (wv * 64) * 8);         \
  } while (0)

  STAGE(0, Bs0, As0);
  __syncthreads();

  for (int kk = 0; kk < 32; kk++) {
    unsigned short* Bc = (kk & 1) ? Bs1 : Bs0;
    unsigned short* Ac = (kk & 1) ? As1 : As0;
    if (kk < 31) {
      unsigned short* Bn = (kk & 1) ? Bs0 : Bs1;
      unsigned short* An = (kk & 1) ? As0 : As1;
      STAGE((kk + 1) * 32, Bn, An);
    }

    short8 af[4], bf[4];
#pragma unroll
    for (int i = 0; i < 4; i++) {
      const int ar = i * 16 + ml;
      af[i] = *(const short8*)(Ac + ar * 32 + (((q + (ar >> 1)) & 3) * 8));
    }
#pragma unroll
    for (int jh = 0; jh < 2; jh++) {
#pragma unroll
      for (int jj = 0; jj < 4; jj++) {
        const int br = wv * 128 + (jh * 4 + jj) * 16 + ml;
        bf[jj] = *(const short8*)(Bc + br * 32 + (((q + (br >> 1)) & 3) * 8));
      }
#pragma unroll
      for (int i = 0; i < 4; i++)
#pragma unroll
        for (int jj = 0; jj < 4; jj++)
          acc[i][jh * 4 + jj] =
              __builtin_amdgcn_mfma_f32_16x16x32_bf16(af[i], bf[jj], acc[i][jh * 4 + jj], 0, 0, 0);
    }
    __syncthreads();
  }

  // ---- epilogue: bias, row sum-of-squares, mask+norm, write ----
  float bv[8];
#pragma unroll
  for (int j = 0; j < 8; j++) bv[j] = bias[wv * 128 + j * 16 + ml];
#pragma unroll
  for (int i = 0; i < 4; i++)
#pragma unroll
    for (int j = 0; j < 8; j++)
#pragma unroll
      for (int r = 0; r < 4; r++) acc[i][j][r] += bv[j];

  // per-row partial ss over this wave's 128 cols; reduce across 16 lanes (same q)
#pragma unroll
  for (int i = 0; i < 4; i++) {
#pragma unroll
    for (int r = 0; r < 4; r++) {
      float ss = 0.0f;
#pragma unroll
      for (int j = 0; j < 8; j++) { float x = acc[i][j][r]; ss = fmaf(x, x, ss); }
      ss += __shfl_xor(ss, 1); ss += __shfl_xor(ss, 2);
      ss += __shfl_xor(ss, 4); ss += __shfl_xor(ss, 8);
      if (ml == 0) redLDS[(i * 16 + q * 4 + r) * 8 + wv] = ss;
    }
  }
  __syncthreads();

  {
    const int row = t >> 3, w = t & 7;   // 512 threads -> 64 rows x 8 partials
    float v = redLDS[row * 8 + w];
    v += __shfl_xor(v, 1); v += __shfl_xor(v, 2); v += __shfl_xor(v, 4);
    if (w == 0) {
      const int gm = mBase + row;
      const int s = gm & (SEQ - 1), b = gm >> 11;
      const float mval = mask[b * SEQ + s];
      // x*mval / max(|mval|*||x||, eps)
      invLDS[row] = mval / fmaxf(fabsf(mval) * sqrtf(v), 1e-12f);
    }
  }
  __syncthreads();

#pragma unroll
  for (int i = 0; i < 4; i++) {
#pragma unroll
    for (int r = 0; r < 4; r++) {
      const int row = i * 16 + q * 4 + r;
      const int gm = mBase + row;
      const int s = gm & (SEQ - 1);
      if (s != 0) {
        const int b = gm >> 11;
        float* orow = out + COLBERT_OFF + (size_t)(b * (SEQ - 1) + s - 1) * HDIM;
        const float iv = invLDS[row];
#pragma unroll
        for (int j = 0; j < 8; j++)
          orow[wv * 128 + j * 16 + ml] = acc[i][j][r] * iv;
      }
    }
  }
}

// ---------------------------------------------------------------------------
extern "C" void kernel_launch(void* const* d_in, const int* in_sizes, int n_in,
                              void* d_out, int out_size, void* d_ws, size_t ws_size,
                              hipStream_t stream) {
  (void)in_sizes; (void)n_in; (void)out_size; (void)ws_size;
  const float* hidden = (const float*)d_in[0];
  const float* attn_mask = (const float*)d_in[1];
  const int* input_ids = (const int*)d_in[2];
  const float* sparse_W = (const float*)d_in[3];
  const float* sparse_b = (const float*)d_in[4];
  const float* colbert_W = (const float*)d_in[5];
  const float* colbert_b = (const float*)d_in[6];
  float* out = (float*)d_out;

  unsigned short* hidden_bf = (unsigned short*)d_ws;                       // 64 MiB
  unsigned short* Wt = (unsigned short*)((char*)d_ws + (size_t)M_TOT * HDIM * 2);

  prep_kernel<<<1552, 256, 0, stream>>>(colbert_W, Wt, out, hidden);
  cast_sparse_kernel<<<M_TOT / 4, 256, 0, stream>>>(
      hidden, sparse_W, sparse_b, input_ids, hidden_bf, out + SPARSE_OFF);
  gemm_norm_kernel<<<M_TOT / 64, 512, LDS_BYTES, stream>>>(
      hidden_bf, Wt, colbert_b, attn_mask, out);
}